// Round 2
// baseline (348.162 us; speedup 1.0000x reference)
//
#include <hip/hip_runtime.h>
#include <math.h>

// SparseGate: B=16384, D=2048, E=64, k=2
#define NROWS 16384
#define DDIM  2048
#define NEXP  64
#define NCOL  128            // fused: 64 gate cols + 64 noise cols

constexpr int BM = 64;       // rows per block
constexpr int BK = 32;       // k per iteration
constexpr int KITERS = DDIM / BK;   // 64
constexpr float TAU = 1e-3f; // margin below which we recheck in fp32

typedef __attribute__((ext_vector_type(8))) short short8;
typedef __attribute__((ext_vector_type(4))) float floatx4;

// ---------------- bf16 split helpers ----------------
__device__ __forceinline__ unsigned short f2bf(float f) {
    unsigned int u = __float_as_uint(f);
    unsigned int r = (u + 0x7FFFu + ((u >> 16) & 1u)) >> 16;
    return (unsigned short)r;
}
__device__ __forceinline__ float bf2f(unsigned short h) {
    return __uint_as_float(((unsigned int)h) << 16);
}

__device__ __forceinline__ float softplus_f(float x) {
    return fmaxf(x, 0.f) + log1pf(expf(-fabsf(x)));
}

// ---------------- top-k + softmax over a 64-lane row ----------------
// Returns this lane's output value; *margin = v_(k) - v_(k+1).
__device__ __forceinline__ float row_gate(int lane, float ew, int k, float* margin)
{
    float cur = ew;
    const float myv = ew;
    float m0 = 0.f, denom = 0.f, vk = 0.f, vk1 = 0.f;
    int selected = 0;
    const int iters = (k < NEXP) ? (k + 1) : k;
    for (int t = 0; t < iters; ++t) {
        float v = cur;
        int idx = lane;
        #pragma unroll
        for (int off = 32; off; off >>= 1) {
            const float ov = __shfl_xor(v, off);
            const int   oi = __shfl_xor(idx, off);
            if (ov > v || (ov == v && oi < idx)) { v = ov; idx = oi; }
        }
        if (t == 0) m0 = v;
        if (t < k) {
            denom += expf(v - m0);
            vk = v;
            if (lane == idx) { selected = 1; cur = -INFINITY; }
        } else {
            vk1 = v;
        }
    }
    *margin = (k < NEXP) ? (vk - vk1) : 1e30f;
    return selected ? expf(myv - m0) / denom : 0.f;
}

// ---------------- weight prep: fp32 -> bf16 hi/lo, k-tile-major ----------------
// Layout: w{hi,lo}T[kt][col][32] with kt = k/32, col = fused col (0..127).
__global__ __launch_bounds__(256) void wprep_kernel(
    const float* __restrict__ gw, const float* __restrict__ nw,
    unsigned short* __restrict__ whiT, unsigned short* __restrict__ wloT,
    int* __restrict__ counter)
{
    if (blockIdx.x == 0 && threadIdx.x == 0) counter[0] = 0;
    const int idx4 = (blockIdx.x * 256 + threadIdx.x) * 4;   // 0..262140
    const int col = idx4 >> 11;          // 0..127
    const int k   = idx4 & 2047;
    const float* src = (col < NEXP) ? (gw + (size_t)col * DDIM + k)
                                    : (nw + (size_t)(col - NEXP) * DDIM + k);
    float4 v = *(const float4*)src;
    float f[4] = {v.x, v.y, v.z, v.w};
    ushort4 h, l;
    unsigned short hu[4], lu[4];
    #pragma unroll
    for (int j = 0; j < 4; ++j) {
        hu[j] = f2bf(f[j]);
        lu[j] = f2bf(f[j] - bf2f(hu[j]));
    }
    h.x = hu[0]; h.y = hu[1]; h.z = hu[2]; h.w = hu[3];
    l.x = lu[0]; l.y = lu[1]; l.z = lu[2]; l.w = lu[3];
    const int pos = (k >> 5) * (NCOL * BK) + col * BK + (k & 31);
    *(ushort4*)&whiT[pos] = h;
    *(ushort4*)&wloT[pos] = l;
}

// ---------------- fused main kernel ----------------
// Grid: 256 blocks x 256 threads. Block computes logits for 64 rows x 128 cols
// via bf16x3 MFMA, then runs the gating epilogue in-block.
union SharedU {
    struct {
        unsigned short xhi[BM * BK];    // [64][32]
        unsigned short xlo[BM * BK];
        unsigned short whi[NCOL * BK];  // [128][32]
        unsigned short wlo[NCOL * BK];
    } t;                                 // 24 KB
    float logits[BM * 132];              // 33 KB (stride 132 kills bank conflicts)
};

__global__ __launch_bounds__(256) void main_kernel(
    const float* __restrict__ x,
    const unsigned short* __restrict__ whiT,
    const unsigned short* __restrict__ wloT,
    const float* __restrict__ noise,
    const int* __restrict__ kptr,
    float* __restrict__ out,
    int* __restrict__ counter,
    int* __restrict__ list)
{
    __shared__ SharedU sm;

    const int tid = threadIdx.x;
    const int row_base = blockIdx.x * BM;

    // staging coords: x tile [64 rows][32 k] fp32 -> hi/lo bf16
    const int sm_m   = tid >> 2;          // 0..63
    const int sm_off = (tid & 3) * 8;     // 0,8,16,24  (k offset)

    // mfma coords
    const int wv     = tid >> 6;          // wave 0..3 -> col group of 32
    const int ln     = tid & 63;
    const int lane15 = ln & 15;
    const int quad   = ln >> 4;

    const float* xrow = x + (size_t)(row_base + sm_m) * DDIM + sm_off;
    const short8* ghT = (const short8*)whiT;   // 512 short8 per k-tile
    const short8* glT = (const short8*)wloT;

    floatx4 acc[4][2];
    #pragma unroll
    for (int rt = 0; rt < 4; ++rt)
        #pragma unroll
        for (int ct = 0; ct < 2; ++ct)
            acc[rt][ct] = (floatx4){0.f, 0.f, 0.f, 0.f};

    // prefetch registers
    float4 px0, px1;
    short8 pw0, pw1, pw2, pw3;

    // iter 0 loads
    px0 = *(const float4*)&xrow[0];
    px1 = *(const float4*)&xrow[4];
    pw0 = ghT[tid * 2];
    pw1 = ghT[tid * 2 + 1];
    pw2 = glT[tid * 2];
    pw3 = glT[tid * 2 + 1];

    const int aoff = lane15 * BK + quad * 8;
    const int boff = (wv * 32 + lane15) * BK + quad * 8;

    for (int it = 0; it < KITERS; ++it) {
        // ---- convert + LDS write (consumes prefetch regs) ----
        {
            float f[8] = {px0.x, px0.y, px0.z, px0.w, px1.x, px1.y, px1.z, px1.w};
            union { unsigned short u[8]; short8 v; } H, L;
            #pragma unroll
            for (int j = 0; j < 8; ++j) {
                H.u[j] = f2bf(f[j]);
                L.u[j] = f2bf(f[j] - bf2f(H.u[j]));
            }
            *(short8*)&sm.t.xhi[sm_m * BK + sm_off] = H.v;
            *(short8*)&sm.t.xlo[sm_m * BK + sm_off] = L.v;
            short8* lh = (short8*)sm.t.whi;
            short8* ll = (short8*)sm.t.wlo;
            lh[tid * 2]     = pw0;
            lh[tid * 2 + 1] = pw1;
            ll[tid * 2]     = pw2;
            ll[tid * 2 + 1] = pw3;
        }
        // ---- issue next iteration's global loads (overlap MFMA phase) ----
        if (it + 1 < KITERS) {
            const float* xp = xrow + (it + 1) * BK;
            px0 = *(const float4*)&xp[0];
            px1 = *(const float4*)&xp[4];
            const int wb = (it + 1) * 512;
            pw0 = ghT[wb + tid * 2];
            pw1 = ghT[wb + tid * 2 + 1];
            pw2 = glT[wb + tid * 2];
            pw3 = glT[wb + tid * 2 + 1];
        }
        __syncthreads();

        // ---- MFMA phase: wave wv covers cols [wv*32, wv*32+32), all 64 rows ----
        short8 ah[4], al[4], bh[2], bl[2];
        #pragma unroll
        for (int rt = 0; rt < 4; ++rt) {
            ah[rt] = *(const short8*)&sm.t.xhi[rt * 16 * BK + aoff];
            al[rt] = *(const short8*)&sm.t.xlo[rt * 16 * BK + aoff];
        }
        #pragma unroll
        for (int ct = 0; ct < 2; ++ct) {
            bh[ct] = *(const short8*)&sm.t.whi[ct * 16 * BK + boff];
            bl[ct] = *(const short8*)&sm.t.wlo[ct * 16 * BK + boff];
        }
        #pragma unroll
        for (int rt = 0; rt < 4; ++rt)
            #pragma unroll
            for (int ct = 0; ct < 2; ++ct) {
                acc[rt][ct] = __builtin_amdgcn_mfma_f32_16x16x32_bf16(ah[rt], bh[ct], acc[rt][ct], 0, 0, 0);
                acc[rt][ct] = __builtin_amdgcn_mfma_f32_16x16x32_bf16(ah[rt], bl[ct], acc[rt][ct], 0, 0, 0);
                acc[rt][ct] = __builtin_amdgcn_mfma_f32_16x16x32_bf16(al[rt], bh[ct], acc[rt][ct], 0, 0, 0);
            }
        __syncthreads();
    }

    // ---- dump logits to LDS (C/D layout: row = quad*4+reg, col = lane15) ----
    #pragma unroll
    for (int rt = 0; rt < 4; ++rt)
        #pragma unroll
        for (int ct = 0; ct < 2; ++ct)
            #pragma unroll
            for (int r = 0; r < 4; ++r)
                sm.logits[(rt * 16 + quad * 4 + r) * 132 + wv * 32 + ct * 16 + lane15] = acc[rt][ct][r];
    __syncthreads();

    // ---- gating epilogue: wave wv handles rows wv*16 .. wv*16+15 ----
    int k = kptr[0];
    if (k < 1) k = 1;
    if (k > NEXP) k = NEXP;

    for (int i = 0; i < 16; ++i) {
        const int r = wv * 16 + i;
        const int row = row_base + r;
        const float clean = sm.logits[r * 132 + ln];
        const float noisy = sm.logits[r * 132 + NEXP + ln];
        const float nz = noise[(size_t)row * NEXP + ln];
        const float ew = clean + nz * softplus_f(noisy);
        float margin;
        const float val = row_gate(ln, ew, k, &margin);
        out[(size_t)row * NEXP + ln] = val;
        if (margin < TAU && ln == 0) {
            const int pos = atomicAdd(counter, 1);
            list[pos] = row;
        }
    }
}

// ---------------- exact fp32 recheck for low-margin rows ----------------
__global__ __launch_bounds__(256) void recheck_kernel(
    const float* __restrict__ x,
    const float* __restrict__ gw,
    const float* __restrict__ nw,
    const float* __restrict__ noise,
    const int* __restrict__ kptr,
    float* __restrict__ out,
    const int* __restrict__ counter,
    const int* __restrict__ list)
{
    __shared__ float xr[DDIM];      // 8 KB
    __shared__ float parts[256];
    __shared__ float lg[NCOL];

    const int tid = threadIdx.x;
    const int cnt = counter[0];

    int k = kptr[0];
    if (k < 1) k = 1;
    if (k > NEXP) k = NEXP;

    for (int ii = blockIdx.x; ii < cnt; ii += gridDim.x) {
        const int row = list[ii];
        // stage x row
        const float4* xs = (const float4*)(x + (size_t)row * DDIM);
        #pragma unroll
        for (int j = 0; j < 2; ++j)
            ((float4*)xr)[tid + j * 256] = xs[tid + j * 256];
        __syncthreads();

        const int e = tid & 127;
        const int half = tid >> 7;
        const float* wc = (e < NEXP) ? (gw + (size_t)e * DDIM)
                                     : (nw + (size_t)(e - NEXP) * DDIM);
        wc += half * 1024;
        const float* xc = xr + half * 1024;
        float s = 0.f;
        #pragma unroll 4
        for (int j = 0; j < 1024; j += 4) {
            float4 w4 = *(const float4*)&wc[j];
            s += xc[j] * w4.x + xc[j + 1] * w4.y + xc[j + 2] * w4.z + xc[j + 3] * w4.w;
        }
        parts[tid] = s;
        __syncthreads();
        if (tid < NCOL) lg[tid] = parts[tid] + parts[tid + 128];
        __syncthreads();
        if (tid < NEXP) {
            const float ew = lg[tid] + noise[(size_t)row * NEXP + tid] * softplus_f(lg[NEXP + tid]);
            float margin;
            const float val = row_gate(tid, ew, k, &margin);
            out[(size_t)row * NEXP + tid] = val;
        }
        __syncthreads();
    }
}

// ---------------- fallback: exact per-row (only if ws too small) ----------------
__global__ __launch_bounds__(256) void naive_kernel(
    const float* __restrict__ x,
    const float* __restrict__ gw,
    const float* __restrict__ nw,
    const float* __restrict__ noise,
    const int* __restrict__ kptr,
    float* __restrict__ out)
{
    const int lane = threadIdx.x & 63;
    const int wave = threadIdx.x >> 6;
    const int row  = blockIdx.x * 4 + wave;
    if (row >= NROWS) return;

    int k = kptr[0];
    if (k < 1) k = 1;
    if (k > NEXP) k = NEXP;

    const float* xr = x  + (size_t)row  * DDIM;
    const float* g  = gw + (size_t)lane * DDIM;
    const float* w2 = nw + (size_t)lane * DDIM;
    float c = 0.f, n = 0.f;
    for (int d = 0; d < DDIM; ++d) {
        const float xv = xr[d];
        c += xv * g[d];
        n += xv * w2[d];
    }
    const float ew = c + noise[(size_t)row * NEXP + lane] * softplus_f(n);
    float margin;
    out[(size_t)row * NEXP + lane] = row_gate(lane, ew, k, &margin);
}

// ---------------------------------------------------------------------------
extern "C" void kernel_launch(void* const* d_in, const int* in_sizes, int n_in,
                              void* d_out, int out_size, void* d_ws, size_t ws_size,
                              hipStream_t stream)
{
    const float* x     = (const float*)d_in[0];
    const float* gw    = (const float*)d_in[1];
    const float* nw    = (const float*)d_in[2];
    const float* noise = (const float*)d_in[3];
    const int*   kptr  = (const int*)d_in[4];
    float* out = (float*)d_out;

    // ws layout: whiT (512 KB) | wloT (512 KB) | counter (256 B) | list (64 KB)
    const size_t need = 512 * 1024 * 2 + 256 + NROWS * sizeof(int);
    if (ws_size < need) {
        hipLaunchKernelGGL(naive_kernel, dim3(NROWS / 4), dim3(256), 0, stream,
                           x, gw, nw, noise, kptr, out);
        return;
    }

    unsigned short* whiT = (unsigned short*)d_ws;
    unsigned short* wloT = whiT + (size_t)NCOL * DDIM;
    int* counter = (int*)((char*)d_ws + 1024 * 1024);
    int* list    = counter + 64;

    hipLaunchKernelGGL(wprep_kernel, dim3(256), dim3(256), 0, stream,
                       gw, nw, whiT, wloT, counter);
    hipLaunchKernelGGL(main_kernel, dim3(NROWS / BM), dim3(256), 0, stream,
                       x, whiT, wloT, noise, kptr, out, counter, list);
    hipLaunchKernelGGL(recheck_kernel, dim3(256), dim3(256), 0, stream,
                       x, gw, nw, noise, kptr, out, counter, list);
}

// Round 4
// 318.687 us; speedup vs baseline: 1.0925x; 1.0925x over previous
//
#include <hip/hip_runtime.h>
#include <math.h>

// SparseGate: B=16384, D=2048, E=64, k=2
#define NROWS 16384
#define DDIM  2048
#define NEXP  64
#define NCOL  128            // fused: 64 gate cols + 64 noise cols

constexpr int KITERS = DDIM / 32;   // 64 K-steps of 32
constexpr float TAU = 1e-3f;        // margin below which we recheck in fp32

typedef __attribute__((ext_vector_type(8))) short short8;
typedef __attribute__((ext_vector_type(4))) float floatx4;

// ---------------- fp32 -> bf16 hi/lo truncation split ----------------
// hi = truncate-to-bf16(f) (exact subtraction), lo = truncate-to-bf16(f - hi).
// Dropped error per product ~2^-16 relative; logit error ~1e-5 << TAU.
__device__ __forceinline__ void split8(const float4 a, const float4 b,
                                       short8* hi, short8* lo)
{
    float f[8] = {a.x, a.y, a.z, a.w, b.x, b.y, b.z, b.w};
    union { unsigned short u[8]; short8 v; } H, L;
    #pragma unroll
    for (int j = 0; j < 8; ++j) {
        const unsigned int u  = __float_as_uint(f[j]);
        const unsigned int hf = u & 0xFFFF0000u;
        const float lf = f[j] - __uint_as_float(hf);   // exact
        H.u[j] = (unsigned short)(u >> 16);
        L.u[j] = (unsigned short)(__float_as_uint(lf) >> 16);
    }
    *hi = H.v; *lo = L.v;
}

__device__ __forceinline__ float softplus_f(float x) {
    return fmaxf(x, 0.f) + log1pf(expf(-fabsf(x)));
}

// ---------------- top-k + softmax over a 64-lane row ----------------
__device__ __forceinline__ float row_gate(int lane, float ew, int k, float* margin)
{
    float cur = ew;
    const float myv = ew;
    float m0 = 0.f, denom = 0.f, vk = 0.f, vk1 = 0.f;
    int selected = 0;
    const int iters = (k < NEXP) ? (k + 1) : k;
    for (int t = 0; t < iters; ++t) {
        float v = cur;
        int idx = lane;
        #pragma unroll
        for (int off = 32; off; off >>= 1) {
            const float ov = __shfl_xor(v, off);
            const int   oi = __shfl_xor(idx, off);
            if (ov > v || (ov == v && oi < idx)) { v = ov; idx = oi; }
        }
        if (t == 0) m0 = v;
        if (t < k) {
            denom += expf(v - m0);
            vk = v;
            if (lane == idx) { selected = 1; cur = -INFINITY; }
        } else {
            vk1 = v;
        }
    }
    *margin = (k < NEXP) ? (vk - vk1) : 1e30f;
    return selected ? expf(myv - m0) / denom : 0.f;
}

// ---------------- weight prep: fp32 -> bf16 hi/lo in MFMA fragment order ----
// whilo layout (shorts): [((col*64 + kt)*4 + quad) * 16] = hi8 | lo8
// where the 8 k's are kt*32 + quad*8 + j. One lane's B-fragment (hi+lo) is a
// single contiguous 32 B region. Total 1 MB (32768 fragments x 32 B).
__global__ __launch_bounds__(256) void wprep_kernel(
    const float* __restrict__ gw, const float* __restrict__ nw,
    unsigned short* __restrict__ whilo, int* __restrict__ counter)
{
    const int g = blockIdx.x * 256 + threadIdx.x;    // 0..32767
    if (g == 0) counter[0] = 0;
    const int col  = g >> 8;                          // 0..127
    const int kt   = (g >> 2) & 63;
    const int quad = g & 3;
    const float* src = (col < NEXP) ? (gw + (size_t)col * DDIM)
                                    : (nw + (size_t)(col - NEXP) * DDIM);
    src += kt * 32 + quad * 8;
    const float4 a = *(const float4*)src;
    const float4 b = *(const float4*)(src + 4);
    short8 hi, lo;
    split8(a, b, &hi, &lo);
    unsigned short* dst = whilo + (size_t)g * 16;     // g == (col*64+kt)*4+quad
    *(short8*)dst       = hi;
    *(short8*)(dst + 8) = lo;
}

// ---------------- fused main kernel: barrier-free K-loop ----------------
// Grid 512 x 256. Block = 32 rows x 128 cols. Wave wv = 32 rows x cols
// [wv*32, wv*32+32). A-fragments straight from global x (fp32->bf16 split
// in-register); B-fragments straight from whilo. No LDS until the epilogue.
__global__ __launch_bounds__(256, 2) void main_kernel(
    const float* __restrict__ x,
    const unsigned short* __restrict__ whilo,
    const float* __restrict__ noise,
    const int* __restrict__ kptr,
    float* __restrict__ out,
    int* __restrict__ counter,
    int* __restrict__ list)
{
    __shared__ float logits[32 * 132];   // 16.9 KB; stride 132 -> 2-way (free)

    const int tid    = threadIdx.x;
    const int wv     = tid >> 6;
    const int ln     = tid & 63;
    const int lane15 = ln & 15;
    const int quad   = ln >> 4;
    const int rowbase = blockIdx.x * 32;

    // A pointers (rt in {0,1}): row = rowbase + rt*16 + lane15, k = kt*32+quad*8
    const float* xp0 = x + (size_t)(rowbase + lane15) * DDIM + quad * 8;
    const float* xp1 = xp0 + (size_t)16 * DDIM;
    // B pointers (ct in {0,1}): col = wv*32 + ct*16 + lane15
    const unsigned short* bp0 = whilo +
        ((size_t)(wv * 32 + lane15) * 256 + quad) * 16;
    const unsigned short* bp1 = bp0 + (size_t)16 * 256 * 16;

    floatx4 acc[2][2];
    #pragma unroll
    for (int rt = 0; rt < 2; ++rt)
        #pragma unroll
        for (int ct = 0; ct < 2; ++ct)
            acc[rt][ct] = (floatx4){0.f, 0.f, 0.f, 0.f};

    // Depth-2 prefetch for A (HBM ~900 cyc), depth-1 for B (L2-resident).
    float4 a0[2][2], a1[2][2];    // [rt][half]
    short8 bcur[2][2];            // [ct][hi/lo]

    a0[0][0] = *(const float4*)(xp0 + 0);
    a0[0][1] = *(const float4*)(xp0 + 4);
    a0[1][0] = *(const float4*)(xp1 + 0);
    a0[1][1] = *(const float4*)(xp1 + 4);
    a1[0][0] = *(const float4*)(xp0 + 32);
    a1[0][1] = *(const float4*)(xp0 + 36);
    a1[1][0] = *(const float4*)(xp1 + 32);
    a1[1][1] = *(const float4*)(xp1 + 36);
    bcur[0][0] = *(const short8*)(bp0 + 0);
    bcur[0][1] = *(const short8*)(bp0 + 8);
    bcur[1][0] = *(const short8*)(bp1 + 0);
    bcur[1][1] = *(const short8*)(bp1 + 8);

    for (int kt = 0; kt < KITERS; ++kt) {
        // convert current A (waits only on loads issued 2 iters ago)
        short8 ahi[2], alo[2];
        split8(a0[0][0], a0[0][1], &ahi[0], &alo[0]);
        split8(a0[1][0], a0[1][1], &ahi[1], &alo[1]);
        short8 bh[2] = {bcur[0][0], bcur[1][0]};
        short8 bl[2] = {bcur[0][1], bcur[1][1]};

        // rotate pipeline, issue next loads
        #pragma unroll
        for (int rt = 0; rt < 2; ++rt)
            #pragma unroll
            for (int h = 0; h < 2; ++h)
                a0[rt][h] = a1[rt][h];
        if (kt + 2 < KITERS) {
            const int o = (kt + 2) * 32;
            a1[0][0] = *(const float4*)(xp0 + o);
            a1[0][1] = *(const float4*)(xp0 + o + 4);
            a1[1][0] = *(const float4*)(xp1 + o);
            a1[1][1] = *(const float4*)(xp1 + o + 4);
        }
        if (kt + 1 < KITERS) {
            const int o = (kt + 1) * 64;
            bcur[0][0] = *(const short8*)(bp0 + o);
            bcur[0][1] = *(const short8*)(bp0 + o + 8);
            bcur[1][0] = *(const short8*)(bp1 + o);
            bcur[1][1] = *(const short8*)(bp1 + o + 8);
        }

        // 12 MFMAs (hi*hi + hi*lo + lo*hi)
        #pragma unroll
        for (int rt = 0; rt < 2; ++rt)
            #pragma unroll
            for (int ct = 0; ct < 2; ++ct) {
                acc[rt][ct] = __builtin_amdgcn_mfma_f32_16x16x32_bf16(ahi[rt], bh[ct], acc[rt][ct], 0, 0, 0);
                acc[rt][ct] = __builtin_amdgcn_mfma_f32_16x16x32_bf16(ahi[rt], bl[ct], acc[rt][ct], 0, 0, 0);
                acc[rt][ct] = __builtin_amdgcn_mfma_f32_16x16x32_bf16(alo[rt], bh[ct], acc[rt][ct], 0, 0, 0);
            }
    }

    // ---- dump logits (C/D layout: col=lane15, row=quad*4+reg) ----
    #pragma unroll
    for (int rt = 0; rt < 2; ++rt)
        #pragma unroll
        for (int ct = 0; ct < 2; ++ct)
            #pragma unroll
            for (int r = 0; r < 4; ++r)
                logits[(rt * 16 + quad * 4 + r) * 132 + wv * 32 + ct * 16 + lane15] = acc[rt][ct][r];
    __syncthreads();   // the only barrier in the kernel

    // ---- gating epilogue: wave wv handles rows wv*8 .. wv*8+7 ----
    int k = kptr[0];
    if (k < 1) k = 1;
    if (k > NEXP) k = NEXP;

    for (int i = 0; i < 8; ++i) {
        const int r   = wv * 8 + i;
        const int row = rowbase + r;
        const float clean = logits[r * 132 + ln];
        const float noisy = logits[r * 132 + NEXP + ln];
        const float nz = noise[(size_t)row * NEXP + ln];
        const float ew = clean + nz * softplus_f(noisy);
        float margin;
        const float val = row_gate(ln, ew, k, &margin);
        out[(size_t)row * NEXP + ln] = val;
        if (margin < TAU && ln == 0) {
            const int pos = atomicAdd(counter, 1);
            list[pos] = row;
        }
    }
}

// ---------------- exact fp32 recheck for low-margin rows ----------------
__global__ __launch_bounds__(256) void recheck_kernel(
    const float* __restrict__ x,
    const float* __restrict__ gw,
    const float* __restrict__ nw,
    const float* __restrict__ noise,
    const int* __restrict__ kptr,
    float* __restrict__ out,
    const int* __restrict__ counter,
    const int* __restrict__ list)
{
    __shared__ float xr[DDIM];      // 8 KB
    __shared__ float parts[256];
    __shared__ float lg[NCOL];

    const int tid = threadIdx.x;
    const int cnt = counter[0];

    int k = kptr[0];
    if (k < 1) k = 1;
    if (k > NEXP) k = NEXP;

    for (int ii = blockIdx.x; ii < cnt; ii += gridDim.x) {
        const int row = list[ii];
        const float4* xs = (const float4*)(x + (size_t)row * DDIM);
        #pragma unroll
        for (int j = 0; j < 2; ++j)
            ((float4*)xr)[tid + j * 256] = xs[tid + j * 256];
        __syncthreads();

        const int e = tid & 127;
        const int half = tid >> 7;
        const float* wc = (e < NEXP) ? (gw + (size_t)e * DDIM)
                                     : (nw + (size_t)(e - NEXP) * DDIM);
        wc += half * 1024;
        const float* xc = xr + half * 1024;
        float s = 0.f;
        #pragma unroll 4
        for (int j = 0; j < 1024; j += 4) {
            float4 w4 = *(const float4*)&wc[j];
            s += xc[j] * w4.x + xc[j + 1] * w4.y + xc[j + 2] * w4.z + xc[j + 3] * w4.w;
        }
        parts[tid] = s;
        __syncthreads();
        if (tid < NCOL) lg[tid] = parts[tid] + parts[tid + 128];
        __syncthreads();
        if (tid < NEXP) {
            const float ew = lg[tid] + noise[(size_t)row * NEXP + tid] * softplus_f(lg[NEXP + tid]);
            float margin;
            const float val = row_gate(tid, ew, k, &margin);
            out[(size_t)row * NEXP + tid] = val;
        }
        __syncthreads();
    }
}

// ---------------- fallback: exact per-row (only if ws too small) ----------------
__global__ __launch_bounds__(256) void naive_kernel(
    const float* __restrict__ x,
    const float* __restrict__ gw,
    const float* __restrict__ nw,
    const float* __restrict__ noise,
    const int* __restrict__ kptr,
    float* __restrict__ out)
{
    const int lane = threadIdx.x & 63;
    const int wave = threadIdx.x >> 6;
    const int row  = blockIdx.x * 4 + wave;
    if (row >= NROWS) return;

    int k = kptr[0];
    if (k < 1) k = 1;
    if (k > NEXP) k = NEXP;

    const float* xr = x  + (size_t)row  * DDIM;
    const float* g  = gw + (size_t)lane * DDIM;
    const float* w2 = nw + (size_t)lane * DDIM;
    float c = 0.f, n = 0.f;
    for (int d = 0; d < DDIM; ++d) {
        const float xv = xr[d];
        c += xv * g[d];
        n += xv * w2[d];
    }
    const float ew = c + noise[(size_t)row * NEXP + lane] * softplus_f(n);
    float margin;
    out[(size_t)row * NEXP + lane] = row_gate(lane, ew, k, &margin);
}

// ---------------------------------------------------------------------------
extern "C" void kernel_launch(void* const* d_in, const int* in_sizes, int n_in,
                              void* d_out, int out_size, void* d_ws, size_t ws_size,
                              hipStream_t stream)
{
    const float* x     = (const float*)d_in[0];
    const float* gw    = (const float*)d_in[1];
    const float* nw    = (const float*)d_in[2];
    const float* noise = (const float*)d_in[3];
    const int*   kptr  = (const int*)d_in[4];
    float* out = (float*)d_out;

    // ws layout: whilo (1 MB: 32768 fragments x 32 B) | counter (@1 MB) | list
    const size_t WHILO_BYTES = (size_t)NCOL * DDIM * 2 * sizeof(unsigned short); // 1 MB
    const size_t need = WHILO_BYTES + 256 + NROWS * sizeof(int);
    if (ws_size < need) {
        hipLaunchKernelGGL(naive_kernel, dim3(NROWS / 4), dim3(256), 0, stream,
                           x, gw, nw, noise, kptr, out);
        return;
    }

    unsigned short* whilo = (unsigned short*)d_ws;
    int* counter = (int*)((char*)d_ws + WHILO_BYTES);
    int* list    = counter + 64;

    hipLaunchKernelGGL(wprep_kernel, dim3(128), dim3(256), 0, stream,
                       gw, nw, whilo, counter);
    hipLaunchKernelGGL(main_kernel, dim3(NROWS / 32), dim3(256), 0, stream,
                       x, whilo, noise, kptr, out, counter, list);
    hipLaunchKernelGGL(recheck_kernel, dim3(256), dim3(256), 0, stream,
                       x, gw, nw, noise, kptr, out, counter, list);
}